// Round 10
// baseline (56.412 us; speedup 1.0000x reference)
//
#include <hip/hip_runtime.h>
#include <cstdint>

// B=8, L=4096, D=1024, W=128. out[b,l,d] = sort128_window( v[b,(l-d)%L,d] )
constexpr int kL    = 4096;
constexpr int kD    = 1024;
constexpr int kW    = 128;
constexpr int kDT   = 32;   // columns per block
constexpr int kROWS = kW + kDT;   // 159 -> 160 rows (1 window + halo)
constexpr int kNIT  = 4;    // windows per block (grid-stride, pipelined)
// band = 160*32*4 = 20,480 B; 1 wave/block; 8 blocks/CU resident (LDS-capped);
// grid = 2048 = exactly 8 per CU, one shot.

// Bitonic sort / merge with all-constant indices (SROA -> registers).
template<int K, int J, int N>
__device__ __forceinline__ void bitonic_stage(float (&e)[N]) {
    #pragma unroll
    for (int i = 0; i < N; ++i) {
        const int ij = i ^ J;
        if (ij > i) {
            const bool up = ((i & K) == 0);
            const float a = e[i], c = e[ij];
            const float lo = fminf(a, c), hi = fmaxf(a, c);
            e[i]  = up ? lo : hi;
            e[ij] = up ? hi : lo;
        }
    }
    if constexpr (J > 1)      bitonic_stage<K, J / 2, N>(e);
    else if constexpr (K < N) bitonic_stage<K * 2, K, N>(e);
}

template<int J, int N>
__device__ __forceinline__ void bitonic_merge(float (&e)[N]) {
    #pragma unroll
    for (int i = 0; i < N; ++i) {
        const int ij = i ^ J;
        if (ij > i) {
            const float a = e[i], c = e[ij];
            e[i]  = fminf(a, c);
            e[ij] = fmaxf(a, c);
        }
    }
    if constexpr (J > 1) bitonic_merge<J / 2, N>(e);
}

__global__ __launch_bounds__(64, 2) void SWD20_sortwin_kernel(
    const float* __restrict__ v, float* __restrict__ out) {
    __shared__ float band[kROWS * kDT];

    const int tid = threadIdx.x;            // = lane (1-wave block)
    const int d0  = blockIdx.x * kDT;
    const int g0  = blockIdx.y * kNIT;      // first window of this block
    const int b   = blockIdx.z;

    const size_t base = (size_t)b * kL * kD;

    const int half = tid >> 5;              // 0: elems 0..63, 1: 64..127
    const int dl   = tid & 31;              // column within tile
    const int sbase = (kDT - 1) - dl + half * 64;
    const float sgn = half ? -1.0f : 1.0f;  // hi half sorts negated (desc)

    // async stage of one 160x32 band via direct-to-LDS (20 loads/lane-16B).
    // LDS dest wave-uniform (HW adds lane*16); linear layout c = it*64+lane.
    auto stage_issue = [&](int w) {
        const int r_lo = w * kW - d0 - (kDT - 1);
        #pragma unroll
        for (int it = 0; it < (kROWS * kDT / 4) / 64; ++it) {
            const int c  = it * 64 + tid;
            const int s  = c >> 3;           // band row (8 float4/row)
            const int fo = (c & 7) << 2;
            const int gr = (r_lo + s + 2 * kL) & (kL - 1);
            const float* src = v + base + (size_t)gr * kD + d0 + fo;
            __builtin_amdgcn_global_load_lds(
                (const __attribute__((address_space(1))) uint32_t*)src,
                (__attribute__((address_space(3))) uint32_t*)&band[it * 256],
                16, 0, 0);
        }
    };

    stage_issue(g0);
    asm volatile("s_waitcnt vmcnt(0)" ::: "memory");

    #pragma unroll 1
    for (int t = 0; t < kNIT; ++t) {
        // ---- extract shifted half-window (bank=dl; 2-way across halves=free)
        float e[64];
        #pragma unroll
        for (int j = 0; j < 64; ++j)
            e[j] = band[(sbase + j) * kDT + dl] * sgn;
        // ds_reads must land before the band is overwritten by next stage
        asm volatile("s_waitcnt lgkmcnt(0)" ::: "memory");

        if (t + 1 < kNIT) stage_issue(g0 + t + 1);  // lands during sort

        // ---- sort 128 across lane pair (sign trick; see R5 derivation) ----
        bitonic_stage<2, 1, 64>(e);
        #pragma unroll
        for (int j = 0; j < 64; ++j) {
            const float r = __shfl_xor(e[j], 32);
            e[j] = fminf(e[j], -r);
        }
        #pragma unroll
        for (int j = 0; j < 64; ++j) e[j] *= sgn;
        bitonic_merge<32, 64>(e);

        // ---- store: fixed j => two contiguous 128B segments; nt = no L2/L3
        // pollution (output never re-read).
        float* op = out + base +
            ((size_t)(g0 + t) * kW + half * 64) * kD + d0 + dl;
        #pragma unroll
        for (int j = 0; j < 64; ++j)
            __builtin_nontemporal_store(e[j], op + (size_t)j * kD);

        // counted wait: 64 newest outstanding = this iter's stores; anything
        // older (the 20 loads for t+1) is forced complete. Stores keep
        // draining under the next iteration's extract+sort.
        if (t + 1 < kNIT)
            asm volatile("s_waitcnt vmcnt(63)" ::: "memory");
    }
}

extern "C" void kernel_launch(void* const* d_in, const int* in_sizes, int n_in,
                              void* d_out, int out_size, void* d_ws, size_t ws_size,
                              hipStream_t stream) {
    const float* v = (const float*)d_in[2];   // inputs: q, k, v — only v used
    float* out = (float*)d_out;
    const int B = in_sizes[2] / (kL * kD);    // = 8
    dim3 grid(kD / kDT, (kL / kW) / kNIT, B); // 32 x 8 x 8 = 2048 blocks
    dim3 block(64);
    hipLaunchKernelGGL(SWD20_sortwin_kernel, grid, block, 0, stream, v, out);
}

// Round 11
// 52.335 us; speedup vs baseline: 1.0779x; 1.0779x over previous
//
#include <hip/hip_runtime.h>
#include <cstdint>

// B=8, L=4096, D=1024, W=128. out[b,l,d] = sort128_window( v[b,(l-d)%L,d] )
constexpr int kL    = 4096;
constexpr int kD    = 1024;
constexpr int kW    = 128;
constexpr int kDT   = 32;   // columns per block
constexpr int kROWS = kW + kDT;   // 159 -> 160 rows (1 window + halo)
// band = 160*32*4 = 20,480 B; 1 wave/block; 8 blocks/CU; no barriers.
//
// XCD-aware 1D remap: id = b + 8*(d0t + 32*w)  ->  xcd = id % 8 = b.
// All 32 d0-tiles of one (w,b) are consecutive ids on ONE XCD, co-resident,
// so their 128B-chunk stores of the same 4KB output rows merge to full lines
// in that XCD's L2 (requires cached stores -> nt dropped). Default dispatch
// had d0 varying fastest across XCDs -> no aggregation -> 2.3 TB/s writes.

// Bitonic sort / merge with all-constant indices (SROA -> registers).
template<int K, int J, int N>
__device__ __forceinline__ void bitonic_stage(float (&e)[N]) {
    #pragma unroll
    for (int i = 0; i < N; ++i) {
        const int ij = i ^ J;
        if (ij > i) {
            const bool up = ((i & K) == 0);
            const float a = e[i], c = e[ij];
            const float lo = fminf(a, c), hi = fmaxf(a, c);
            e[i]  = up ? lo : hi;
            e[ij] = up ? hi : lo;
        }
    }
    if constexpr (J > 1)      bitonic_stage<K, J / 2, N>(e);
    else if constexpr (K < N) bitonic_stage<K * 2, K, N>(e);
}

template<int J, int N>
__device__ __forceinline__ void bitonic_merge(float (&e)[N]) {
    #pragma unroll
    for (int i = 0; i < N; ++i) {
        const int ij = i ^ J;
        if (ij > i) {
            const float a = e[i], c = e[ij];
            e[i]  = fminf(a, c);
            e[ij] = fmaxf(a, c);
        }
    }
    if constexpr (J > 1) bitonic_merge<J / 2, N>(e);
}

__global__ __launch_bounds__(64, 2) void SWD20_sortwin_kernel(
    const float* __restrict__ v, float* __restrict__ out) {
    __shared__ float band[kROWS * kDT];

    const int tid = threadIdx.x;            // = lane (1-wave block)
    // decode XCD-friendly 1D id: b fastest (xcd=b), then d0-tile, then window
    const int id  = blockIdx.x;
    const int b   = id & 7;
    const int d0  = ((id >> 3) & 31) * kDT;
    const int w0  = id >> 8;

    const size_t base = (size_t)b * kL * kD;
    const int r_lo = w0 * kW - d0 - (kDT - 1);

    // ---- stage band: 160 rows x 32 cols via direct-to-LDS (20 iters).
    // LDS dest wave-uniform (HW adds lane*16); linear layout c = it*64+lane.
    #pragma unroll
    for (int it = 0; it < (kROWS * kDT / 4) / 64; ++it) {
        const int c  = it * 64 + tid;
        const int s  = c >> 3;               // band row (8 float4/row)
        const int fo = (c & 7) << 2;
        const int gr = (r_lo + s + 2 * kL) & (kL - 1);
        const float* src = v + base + (size_t)gr * kD + d0 + fo;
        __builtin_amdgcn_global_load_lds(
            (const __attribute__((address_space(1))) uint32_t*)src,
            (__attribute__((address_space(3))) uint32_t*)&band[it * 256],
            16, 0, 0);
    }
    // single-wave block: own vmcnt(0) makes LDS data visible; no barrier.
    asm volatile("s_waitcnt vmcnt(0)" ::: "memory");

    // ---- 2 lanes per column: lane l elems 0..63, lane l+32 elems 64..127 --
    const int half = tid >> 5;
    const int dl   = tid & 31;
    const int sbase = (kDT - 1) - dl + half * 64;
    const float sgn = half ? -1.0f : 1.0f;  // hi half sorts negated (desc)

    // extract: bank = dl, lane & lane+32 share a bank (2-way = free)
    float e[64];
    #pragma unroll
    for (int j = 0; j < 64; ++j)
        e[j] = band[(sbase + j) * kDT + dl] * sgn;

    // sort own 64 ascending in storage (hi: real-descending via sign)
    bitonic_stage<2, 1, 64>(e);
    // cross-lane stage (j=64 of the 128 network): uniform fminf, no branch
    #pragma unroll
    for (int j = 0; j < 64; ++j) {
        const float r = __shfl_xor(e[j], 32);
        e[j] = fminf(e[j], -r);
    }
    #pragma unroll
    for (int j = 0; j < 64; ++j) e[j] *= sgn;   // restore real values
    bitonic_merge<32, 64>(e);                   // final lane-local merge

    // ---- store: fixed j => two contiguous 128B segments per instr.
    // REGULAR stores (not nt): co-resident same-XCD blocks covering the other
    // d0 tiles merge these into full 4KB lines in L2 before HBM eviction.
    float* op = out + base + ((size_t)w0 * kW + half * 64) * kD + d0 + dl;
    #pragma unroll
    for (int j = 0; j < 64; ++j)
        op[(size_t)j * kD] = e[j];
}

extern "C" void kernel_launch(void* const* d_in, const int* in_sizes, int n_in,
                              void* d_out, int out_size, void* d_ws, size_t ws_size,
                              hipStream_t stream) {
    const float* v = (const float*)d_in[2];   // inputs: q, k, v — only v used
    float* out = (float*)d_out;
    const int B = in_sizes[2] / (kL * kD);    // = 8
    const int nblk = (kD / kDT) * (kL / kW) * B;  // 32*32*8 = 8192
    dim3 grid(nblk);                           // 1D: id = b + 8*(d0t + 32*w)
    dim3 block(64);
    hipLaunchKernelGGL(SWD20_sortwin_kernel, grid, block, 0, stream, v, out);
}